// Round 1
// baseline (159.710 us; speedup 1.0000x reference)
//
#include <hip/hip_runtime.h>
#include <math.h>

// Per element: rel = qinv(a) * idd ; theta = 2*atan2(|v_rel|, w_rel)
// contribution = theta^2 (or (2*|v|/w)^2 when |v| < 1e-6)
// output scalar = sqrt(sum over all elements)

__global__ __launch_bounds__(256) void geo_loss_kernel(
        const float4* __restrict__ a,
        const float4* __restrict__ idd,
        float* __restrict__ ws, int n) {
    float acc = 0.0f;
    int stride = gridDim.x * blockDim.x;
    for (int i = blockIdx.x * blockDim.x + threadIdx.x; i < n; i += stride) {
        float4 qa = a[i];
        float4 qb = idd[i];
        // q1 = qinv(a) = (w, -x, -y, -z); q2 = idd
        float w1 = qa.x, x1 = -qa.y, y1 = -qa.z, z1 = -qa.w;
        float w2 = qb.x, x2 = qb.y,  y2 = qb.z,  z2 = qb.w;
        // qmul(q1, q2)
        float w  = w1*w2 - (x1*x2 + y1*y2 + z1*z2);
        float vx = w1*x2 + w2*x1 + (y1*z2 - z1*y2);
        float vy = w1*y2 + w2*y1 + (z1*x2 - x1*z2);
        float vz = w1*z2 + w2*z1 + (x1*y2 - y1*x2);
        float nv2 = vx*vx + vy*vy + vz*vz;
        float nv = sqrtf(nv2);
        float t;
        if (nv < 1e-6f) {
            float s = 2.0f / w;      // scale = 2/w, |tangent|^2 = nv^2 * s^2
            t = nv2 * s * s;
        } else {
            float theta = 2.0f * atan2f(nv, w);  // |tangent|^2 = theta^2
            t = theta * theta;
        }
        acc += t;
    }
    // wave-64 reduction
    #pragma unroll
    for (int off = 32; off > 0; off >>= 1)
        acc += __shfl_down(acc, off, 64);
    __shared__ float smem[4];        // 256 threads = 4 waves
    int lane = threadIdx.x & 63;
    int wid  = threadIdx.x >> 6;
    if (lane == 0) smem[wid] = acc;
    __syncthreads();
    if (threadIdx.x == 0) {
        float s = smem[0] + smem[1] + smem[2] + smem[3];
        atomicAdd(ws, s);            // device-scope by default on CDNA
    }
}

__global__ void finalize_kernel(const float* __restrict__ ws,
                                float* __restrict__ out) {
    out[0] = sqrtf(ws[0]);
}

extern "C" void kernel_launch(void* const* d_in, const int* in_sizes, int n_in,
                              void* d_out, int out_size, void* d_ws, size_t ws_size,
                              hipStream_t stream) {
    const float4* a   = (const float4*)d_in[0];
    const float4* idd = (const float4*)d_in[1];
    int n = in_sizes[0] / 4;         // 4,000,000 quaternions
    float* ws = (float*)d_ws;

    // d_ws is re-poisoned to 0xAA before every timed launch — zero it.
    hipMemsetAsync(ws, 0, sizeof(float), stream);

    const int block = 256;
    const int grid  = 2048;          // 8 blocks/CU worth of waves, ~7.6 elem/thread
    geo_loss_kernel<<<grid, block, 0, stream>>>(a, idd, ws, n);
    finalize_kernel<<<1, 1, 0, stream>>>(ws, (float*)d_out);
}